// Round 1
// baseline (293.962 us; speedup 1.0000x reference)
//
#include <hip/hip_runtime.h>
#include <hip/hip_bf16.h>

// B=8, S=1024, H=16, D=64, E=1024. I/O fp32; internal bf16 MFMA.
// attn = softmax over QUERY axis C (per key row c) of tril(K Q^T)/8.
// Two-pass: l_c = sum_{C<=c} exp(s_cC/8); V pre-scaled by 1/l_c (vscale);
// then z[C] = sum_{c>=C} exp(s_cC/8) * (v_c / l_c).
// R9: attn kernels rebuilt as 4-wave (256-thr) cooperative blocks to fix
// latency-bound 2-waves/SIMD occupancy. attn_av: wave w = query tile t=w
// (scores) + head-dim quarter n=w (PV), P shared via LDS, 1 barrier per
// 32-key step, ~110 VGPR/wave. attn_stats: waves split query tiles mod 4,
// LDS partial-l reduce. GEMMs unchanged (BK=64 + swizzle).

#define SEQ 1024
#define DH 64
#define NH 16
#define EMB 1024
#define SCALE 0.18033688011112042f  // 0.125 * log2(e)
#define PSTR 40                     // P row stride (u16), 80B = 16B-aligned

#define ZEROM 0
#define DIAGM 1
#define FULLM 2

typedef float f32x4 __attribute__((ext_vector_type(4)));
typedef __bf16 bf16x8 __attribute__((ext_vector_type(8)));
typedef unsigned short u16x8 __attribute__((ext_vector_type(8)));

__device__ __forceinline__ unsigned short f2bf(float f) {
  union { float f; unsigned int u; } v; v.f = f;
  unsigned int u = v.u;
  return (unsigned short)((u + 0x7fffu + ((u >> 16) & 1u)) >> 16);  // RNE
}
__device__ __forceinline__ unsigned short f2bf_fast(float f) {
  union { float f; unsigned int u; } v; v.f = f;
  return (unsigned short)((v.u + 0x8000u) >> 16);  // round-half-up (p>=0)
}
__device__ __forceinline__ float bf2f(unsigned short u) {
  union { unsigned int u; float f; } v; v.u = ((unsigned int)u) << 16; return v.f;
}

__device__ __forceinline__ u16x8 ld8_f32_bf16(const float* g) {
  const float4 a = *(const float4*)g;
  const float4 b = *(const float4*)(g + 4);
  u16x8 r;
  r[0] = f2bf(a.x); r[1] = f2bf(a.y); r[2] = f2bf(a.z); r[3] = f2bf(a.w);
  r[4] = f2bf(b.x); r[5] = f2bf(b.y); r[6] = f2bf(b.z); r[7] = f2bf(b.w);
  return r;
}

__device__ __forceinline__ void gl_lds16(const void* g, void* l) {
  __builtin_amdgcn_global_load_lds(
      (const __attribute__((address_space(1))) void*)g,
      (__attribute__((address_space(3))) void*)l, 16, 0, 0);
}

// ---------------- fp32 -> bf16 conversion of X and weights ----------------
__global__ __launch_bounds__(256) void cvt_bf16(
    const float* __restrict__ X, const float* __restrict__ Wk,
    const float* __restrict__ Wq, const float* __restrict__ Wv,
    const float* __restrict__ Wo,
    unsigned short* __restrict__ Xb, unsigned short* __restrict__ Wkb,
    unsigned short* __restrict__ Wqb, unsigned short* __restrict__ Wvb,
    unsigned short* __restrict__ Wob)
{
  const size_t i = ((size_t)blockIdx.x * 256 + threadIdx.x) * 8;
  const float* src; unsigned short* dst; size_t off;
  if (i < 8388608) { src = X; dst = Xb; off = i; }
  else {
    const size_t j = i - 8388608;
    const int sel = (int)(j >> 20); off = j & 1048575;
    src = (sel == 0) ? Wk : (sel == 1) ? Wq : (sel == 2) ? Wv : Wo;
    dst = (sel == 0) ? Wkb : (sel == 1) ? Wqb : (sel == 2) ? Wvb : Wob;
  }
  *(u16x8*)(dst + off) = ld8_f32_bf16(src + off);
}

// ---------------- GEMM core (BK=64, xor-swizzled LDS) ----------------
#define GEMM_BK64_BODY(Aptr, Bptr)                                              \
  f32x4 acc[4][4] = {};                                                         \
  const int srow = lane >> 3;                                                   \
  const int scol = (((lane & 7) ^ srow)) * 8;                                   \
  const unsigned short* Ag = (Aptr) + (size_t)(mt0 + wave * 32 + srow) * EMB + scol; \
  const unsigned short* Bg = (Bptr) + (size_t)(n0 + wave * 32 + srow) * EMB + scol;  \
  char* lA = (char*)As + wave * 4096;                                           \
  char* lB = (char*)Bs + wave * 4096;                                           \
  for (int k0 = 0; k0 < EMB; k0 += 64) {                                        \
    __syncthreads();                                                            \
    _Pragma("unroll")                                                           \
    for (int ch = 0; ch < 4; ch++) {                                            \
      gl_lds16(Ag + (size_t)ch * 8 * EMB + k0, lA + ch * 1024);                 \
      gl_lds16(Bg + (size_t)ch * 8 * EMB + k0, lB + ch * 1024);                 \
    }                                                                           \
    __syncthreads();                                                            \
    _Pragma("unroll")                                                           \
    for (int half = 0; half < 2; half++) {                                      \
      bf16x8 af[4], bfr[4];                                                     \
      _Pragma("unroll")                                                         \
      for (int t = 0; t < 4; t++) {                                             \
        const int ra = wm * 64 + t * 16 + fr;                                   \
        const int rb = wn * 64 + t * 16 + fr;                                   \
        af[t]  = *(const bf16x8*)&As[ra * 64 + (((half * 4 + quad) ^ (ra & 7)) * 8)]; \
        bfr[t] = *(const bf16x8*)&Bs[rb * 64 + (((half * 4 + quad) ^ (rb & 7)) * 8)]; \
      }                                                                         \
      _Pragma("unroll")                                                         \
      for (int i = 0; i < 4; i++)                                               \
        _Pragma("unroll")                                                       \
        for (int j = 0; j < 4; j++)                                             \
          acc[i][j] = __builtin_amdgcn_mfma_f32_16x16x32_bf16(af[i], bfr[j], acc[i][j], 0, 0, 0); \
    }                                                                           \
  }

// ---------------- GEMM: QKV projection ----------------
__global__ __launch_bounds__(256) void gemm_qkv(
    const unsigned short* __restrict__ X,
    const unsigned short* __restrict__ Wk,
    const unsigned short* __restrict__ Wq,
    const unsigned short* __restrict__ Wv,
    unsigned short* __restrict__ Kb,
    unsigned short* __restrict__ Qb,
    unsigned short* __restrict__ Vt)
{
  __shared__ __align__(16) unsigned short As[128 * 64];
  __shared__ __align__(16) unsigned short Bs[128 * 64];
  const int mt0 = blockIdx.x * 128;
  const int nt = blockIdx.y;
  const int sel = nt >> 3;
  const int n0 = (nt & 7) * 128;
  const unsigned short* W = (sel == 0) ? Wk : (sel == 1) ? Wq : Wv;

  const int tid = threadIdx.x;
  const int wave = tid >> 6, lane = tid & 63;
  const int wm = wave >> 1, wn = wave & 1;
  const int fr = lane & 15, quad = lane >> 4;

  GEMM_BK64_BODY(X, W)

  const int rl = quad * 4;
  if (sel < 2) {
    unsigned short* Dst = (sel == 0) ? Kb : Qb;
#pragma unroll
    for (int i = 0; i < 4; i++) {
      const int col = n0 + wn * 64 + i * 16 + fr;
      const int a = col >> 6, h = col & 63;
#pragma unroll
      for (int j = 0; j < 4; j++) {
        const int rowb = mt0 + wm * 64 + j * 16 + rl;
#pragma unroll
        for (int r = 0; r < 4; r++) {
          const int row = rowb + r;
          const int b = row >> 10, s = row & 1023;
          Dst[(size_t)((b * NH + a) * SEQ + s) * DH + h] = f2bf(acc[j][i][r]);
        }
      }
    }
  } else {
#pragma unroll
    for (int i = 0; i < 4; i++) {
      const int col = n0 + wn * 64 + i * 16 + fr;
      const int a = col >> 6, h = col & 63;
#pragma unroll
      for (int j = 0; j < 4; j++) {
        const int rowb = mt0 + wm * 64 + j * 16 + rl;
#pragma unroll
        for (int r = 0; r < 4; r++) {
          const int row = rowb + r;
          const int b = row >> 10, s = row & 1023;
          Vt[(size_t)((b * NH + a) * DH + h) * SEQ + s] = f2bf(acc[j][i][r]);
        }
      }
    }
  }
}

// ---------------- GEMM: output projection (bf16 in, fp32 out) ----------------
__global__ __launch_bounds__(256) void gemm_out(
    const unsigned short* __restrict__ Z,
    const unsigned short* __restrict__ Wo,
    float* __restrict__ Out)
{
  __shared__ __align__(16) unsigned short As[128 * 64];
  __shared__ __align__(16) unsigned short Bs[128 * 64];
  const int mt0 = blockIdx.x * 128;
  const int n0 = blockIdx.y * 128;

  const int tid = threadIdx.x;
  const int wave = tid >> 6, lane = tid & 63;
  const int wm = wave >> 1, wn = wave & 1;
  const int fr = lane & 15, quad = lane >> 4;

  GEMM_BK64_BODY(Z, Wo)

  const int rl = quad * 4;
#pragma unroll
  for (int i = 0; i < 4; i++) {
    const int col = n0 + wn * 64 + i * 16 + fr;
#pragma unroll
    for (int j = 0; j < 4; j++) {
      const int rowb = mt0 + wm * 64 + j * 16 + rl;
#pragma unroll
      for (int r = 0; r < 4; r++)
        Out[(size_t)(rowb + r) * EMB + col] = acc[j][i][r];
    }
  }
}

// ---------------- stats tile: accumulate exp into l4 ----------------
__device__ __forceinline__ void st_tile(
    const bf16x8* ka, const bf16x8* q, float* l4, int mode, int fr, int quad)
{
  f32x4 a = {0.f, 0.f, 0.f, 0.f};
  a = __builtin_amdgcn_mfma_f32_16x16x32_bf16(ka[0], q[0], a, 0, 0, 0);
  a = __builtin_amdgcn_mfma_f32_16x16x32_bf16(ka[1], q[1], a, 0, 0, 0);
#pragma unroll
  for (int i = 0; i < 4; i++) {
    const float e = exp2f(a[i] * SCALE);
    l4[i] += (mode == FULLM || fr <= quad * 4 + i) ? e : 0.f;
  }
}

// ---------------- Pass 1: l_c = sum_{C<=c} exp(s_cC/8) ----------------
// 4-wave blocks: 64 c-rows per block, waves split query tiles (m mod 4 in
// the full region; wave w takes diag query tile w). Partial l summed via
// LDS. grid (128 heads, 16 chunks), 256 thr. y=0 -> heaviest (jj=15).
__global__ __launch_bounds__(256, 4) void attn_stats(
    const unsigned short* __restrict__ Kb, const unsigned short* __restrict__ Qb,
    float* __restrict__ Ls)
{
  __shared__ float lsum[4][16][64];  // [wave][s*4+i][lane] - conflict-free
  const int head = blockIdx.x;
  const int jj = 15 - (int)blockIdx.y;
  const int cw = jj * 64;
  const int tid = threadIdx.x;
  const int w = tid >> 6;
  const int lane = tid & 63;
  const int fr = lane & 15, quad = lane >> 4;
  const unsigned short* Kl = Kb + (size_t)head * (SEQ * DH) + (size_t)fr * DH + quad * 8;
  const unsigned short* Ql = Qb + (size_t)head * (SEQ * DH) + (size_t)fr * DH + quad * 8;

  // K fragments for this block's 64 c-rows (all waves load the same -> L1 hit)
  bf16x8 ka[4][2];
#pragma unroll
  for (int s = 0; s < 4; s++)
#pragma unroll
    for (int h = 0; h < 2; h++)
      ka[s][h] = *(const bf16x8*)(Kl + (size_t)(cw + s * 16) * DH + h * 32);

  float l[4][4] = {};

  // full region: 16-query tiles m = w + 4*i, i in [0, jj). All tiles FULL.
  if (jj > 0) {
    const unsigned short* q0p = Ql + (size_t)(w * 16) * DH;
    bf16x8 qc0 = *(const bf16x8*)(q0p);
    bf16x8 qc1 = *(const bf16x8*)(q0p + 32);
    for (int i = 0; i < jj; i++) {
      bf16x8 qn0 = qc0, qn1 = qc1;
      if (i + 1 < jj) {
        const unsigned short* qp = Ql + (size_t)((w + 4 * (i + 1)) * 16) * DH;
        qn0 = *(const bf16x8*)(qp);
        qn1 = *(const bf16x8*)(qp + 32);
      }
      bf16x8 qq[2] = {qc0, qc1};
#pragma unroll
      for (int s = 0; s < 4; s++)
        st_tile(ka[s], qq, l[s], FULLM, fr, quad);
      qc0 = qn0; qc1 = qn1;
    }
  }

  // diagonal 64x64 block: wave w covers queries [cw + w*16, cw + w*16 + 16)
  {
    const unsigned short* qp = Ql + (size_t)(cw + w * 16) * DH;
    bf16x8 qd[2];
    qd[0] = *(const bf16x8*)(qp);
    qd[1] = *(const bf16x8*)(qp + 32);
#pragma unroll
    for (int s = 0; s < 4; s++) {
      if (s >= w)
        st_tile(ka[s], qd, l[s], (s == w) ? DIAGM : FULLM, fr, quad);
    }
  }

  // cross-wave reduce, then shfl-over-fr reduce (wave 0)
#pragma unroll
  for (int s = 0; s < 4; s++)
#pragma unroll
    for (int i = 0; i < 4; i++)
      lsum[w][s * 4 + i][lane] = l[s][i];
  __syncthreads();
  if (w == 0) {
#pragma unroll
    for (int s = 0; s < 4; s++)
#pragma unroll
      for (int i = 0; i < 4; i++) {
        float v = lsum[0][s * 4 + i][lane] + lsum[1][s * 4 + i][lane]
                + lsum[2][s * 4 + i][lane] + lsum[3][s * 4 + i][lane];
        v += __shfl_xor(v, 1); v += __shfl_xor(v, 2);
        v += __shfl_xor(v, 4); v += __shfl_xor(v, 8);
        if (fr == 0) Ls[head * SEQ + cw + s * 16 + quad * 4 + i] = v;
      }
  }
}

// ---------------- V row-scale: Vt[head][h][s] *= 1/l_s ----------------
__global__ __launch_bounds__(256) void vscale(
    unsigned short* __restrict__ Vt, const float* __restrict__ Ls)
{
  const size_t i = ((size_t)blockIdx.x * 256 + threadIdx.x) * 8;  // < 8388608
  const int head = (int)(i >> 16);
  const int s = (int)(i & 1023);
  const float* lp = Ls + (head << 10) + s;
  const u16x8 v = *(const u16x8*)(Vt + i);
  const float4 la = *(const float4*)lp;
  const float4 lb = *(const float4*)(lp + 4);
  const float lv[8] = {la.x, la.y, la.z, la.w, lb.x, lb.y, lb.z, lb.w};
  u16x8 o;
#pragma unroll
  for (int j = 0; j < 8; j++)
    o[j] = f2bf(bf2f(v[j]) * __builtin_amdgcn_rcpf(lv[j]));
  *(u16x8*)(Vt + i) = o;
}

// ---------------- av score tile -> LDS (V pre-scaled) ----------------
__device__ __forceinline__ void av_tile(
    const bf16x8* ka, const bf16x8* bq,
    unsigned short* __restrict__ pw, int mode, int fr, int quad)
{
  if (mode == ZEROM) { *(uint2*)pw = make_uint2(0u, 0u); return; }
  f32x4 acc = {0.f, 0.f, 0.f, 0.f};
  acc = __builtin_amdgcn_mfma_f32_16x16x32_bf16(ka[0], bq[0], acc, 0, 0, 0);
  acc = __builtin_amdgcn_mfma_f32_16x16x32_bf16(ka[1], bq[1], acc, 0, 0, 0);
  unsigned short us[4];
#pragma unroll
  for (int i = 0; i < 4; i++) {
    float p = exp2f(acc[i] * SCALE);
    if (mode == DIAGM && (quad * 4 + i < fr)) p = 0.f;
    us[i] = f2bf_fast(p);
  }
  uint2 pk;
  pk.x = (unsigned)us[0] | ((unsigned)us[1] << 16);
  pk.y = (unsigned)us[2] | ((unsigned)us[3] << 16);
  *(uint2*)pw = pk;
}

// ---------------- Pass 2: z = P^T (V/l) ----------------
// 4-wave cooperative blocks: wave w computes score tiles for query tile
// t=w (-> LDS P stripe) and PV for head-dim quarter n=w (reads all P
// stripes). Double-buffered P, one barrier per 32-key step; global K/V
// prefetch issued right after each barrier. grid (128 heads, 16 chunks),
// 256 thr. Chunk 0 heaviest, first.
__global__ __launch_bounds__(256, 3) void attn_av(
    const unsigned short* __restrict__ Kb, const unsigned short* __restrict__ Qb,
    const unsigned short* __restrict__ Vt, unsigned short* __restrict__ Z)
{
  __shared__ __align__(16) unsigned short P[2][4][16 * PSTR];
  const int head = blockIdx.x;
  const int tid = threadIdx.x;
  const int w = tid >> 6;        // wave: query tile t=w, head-dim quarter n=w
  const int lane = tid & 63;
  const int fr = lane & 15, quad = lane >> 4;
  const int Cw = blockIdx.y * 64;
  const unsigned short* Kl = Kb + (size_t)head * (SEQ * DH) + (size_t)fr * DH + quad * 8;
  const unsigned short* Vl = Vt + (size_t)head * (SEQ * DH)
      + (size_t)(w * 16 + fr) * SEQ + quad * 8;

  // Q fragment for this wave's query tile (queries Cw + w*16 + fr)
  bf16x8 bq[2];
  {
    const unsigned short* Ql = Qb + (size_t)head * (SEQ * DH)
        + (size_t)(Cw + w * 16 + fr) * DH + quad * 8;
    bq[0] = *(const bf16x8*)(Ql);
    bq[1] = *(const bf16x8*)(Ql + 32);
  }

  f32x4 zacc[4] = {};  // t = 0..3 for this wave's n=w quarter
  bf16x8 kA0[2], kA1[2], kB0[2], kB1[2], vA, vB;

  unsigned short* const Pw0 = &P[0][w][fr * PSTR + quad * 4];
  unsigned short* const Pw1 = &P[1][w][fr * PSTR + quad * 4];

  {  // prologue: scores for keys [Cw, Cw+32) -> P[0]
    bf16x8 kp0[2], kp1[2];
#pragma unroll
    for (int h = 0; h < 2; h++) {
      kp0[h] = *(const bf16x8*)(Kl + (size_t)Cw * DH + h * 32);
      kp1[h] = *(const bf16x8*)(Kl + (size_t)(Cw + 16) * DH + h * 32);
    }
    av_tile(kp0, bq, Pw0, (w == 0) ? DIAGM : ZEROM, fr, quad);
    av_tile(kp1, bq, Pw0 + 16, (w == 0) ? FULLM : ((w == 1) ? DIAGM : ZEROM), fr, quad);
  }
  // kB: keys [Cw+32, Cw+64) (always exists: Cw <= SEQ-64)
#pragma unroll
  for (int h = 0; h < 2; h++) {
    kB0[h] = *(const bf16x8*)(Kl + (size_t)(Cw + 32) * DH + h * 32);
    kB1[h] = *(const bf16x8*)(Kl + (size_t)(Cw + 48) * DH + h * 32);
  }
  vA = *(const bf16x8*)(Vl + Cw);

  for (int cb = Cw; cb < SEQ; cb += 64) {
    {  // step A: scores keys [cb+32,cb+64) -> P[1]; PV(P[0], vA) keys [cb,cb+32)
      __syncthreads();  // P[0] writes visible; prior P[1] reads done
      const int nk = cb + 64;
      if (nk < SEQ) {
#pragma unroll
        for (int h = 0; h < 2; h++) {
          kA0[h] = *(const bf16x8*)(Kl + (size_t)nk * DH + h * 32);
          kA1[h] = *(const bf16x8*)(Kl + (size_t)(nk + 16) * DH + h * 32);
        }
      }
      vB = *(const bf16x8*)(Vl + (cb + 32));
      int m0 = FULLM, m1 = FULLM;
      if (cb == Cw) {
        m0 = (w < 2) ? FULLM : ((w == 2) ? DIAGM : ZEROM);
        m1 = (w < 3) ? FULLM : DIAGM;
      }
      av_tile(kB0, bq, Pw1, m0, fr, quad);
      av_tile(kB1, bq, Pw1 + 16, m1, fr, quad);
      bf16x8 pf[4];
#pragma unroll
      for (int t = 0; t < 4; t++)
        pf[t] = *(const bf16x8*)&P[0][t][fr * PSTR + quad * 8];
#pragma unroll
      for (int t = 0; t < 4; t++)
        zacc[t] = __builtin_amdgcn_mfma_f32_16x16x32_bf16(pf[t], vA, zacc[t], 0, 0, 0);
    }
    {  // step B: scores keys [cb+64,cb+96) -> P[0]; PV(P[1], vB) keys [cb+32,cb+64)
      __syncthreads();  // P[1] writes visible; P[0] reads done
      const bool hasC = (cb + 64 < SEQ);
      if (hasC) {
        const int nk = cb + 96;
        if (nk < SEQ) {
#pragma unroll
          for (int h = 0; h < 2; h++) {
            kB0[h] = *(const bf16x8*)(Kl + (size_t)nk * DH + h * 32);
            kB1[h] = *(const bf16x8*)(Kl + (size_t)(nk + 16) * DH + h * 32);
          }
        }
        vA = *(const bf16x8*)(Vl + (cb + 64));
        av_tile(kA0, bq, Pw0, FULLM, fr, quad);
        av_tile(kA1, bq, Pw0 + 16, FULLM, fr, quad);
      }
      bf16x8 pf[4];
#pragma unroll
      for (int t = 0; t < 4; t++)
        pf[t] = *(const bf16x8*)&P[1][t][fr * PSTR + quad * 8];
#pragma unroll
      for (int t = 0; t < 4; t++)
        zacc[t] = __builtin_amdgcn_mfma_f32_16x16x32_bf16(pf[t], vB, zacc[t], 0, 0, 0);
    }
  }

  const int b = head >> 4, a = head & 15;
  const int f = a * DH + w * 16 + fr;
#pragma unroll
  for (int t = 0; t < 4; t++)
#pragma unroll
    for (int i = 0; i < 4; i++) {
      const int C = Cw + t * 16 + quad * 4 + i;
      Z[((size_t)(b * SEQ + C) << 10) + f] = f2bf(zacc[t][i]);
    }
}

// ---------------- launch ----------------
extern "C" void kernel_launch(void* const* d_in, const int* in_sizes, int n_in,
                              void* d_out, int out_size, void* d_ws, size_t ws_size,
                              hipStream_t stream)
{
  const float* x  = (const float*)d_in[0];
  const float* wk = (const float*)d_in[1];
  const float* wq = (const float*)d_in[2];
  const float* wv = (const float*)d_in[3];
  const float* wo = (const float*)d_in[4];
  float* out = (float*)d_out;
  char* ws = (char*)d_ws;

  unsigned short* Xb  = (unsigned short*)(ws);            // 16 MB (aliased by Zb)
  unsigned short* Zb  = (unsigned short*)(ws);
  unsigned short* Kb  = (unsigned short*)(ws + 16777216);
  unsigned short* Qb  = (unsigned short*)(ws + 33554432);
  unsigned short* Vtb = (unsigned short*)(ws + 50331648);
  unsigned short* Wkb = (unsigned short*)(ws + 67108864);
  unsigned short* Wqb = (unsigned short*)(ws + 69206016);
  unsigned short* Wvb = (unsigned short*)(ws + 71303168);
  unsigned short* Wob = (unsigned short*)(ws + 73400320);
  float* Ls = (float*)(ws + 75497472);

  cvt_bf16<<<dim3(6144), 256, 0, stream>>>(x, wk, wq, wv, wo, Xb, Wkb, Wqb, Wvb, Wob);
  gemm_qkv<<<dim3(64, 24), 256, 0, stream>>>(Xb, Wkb, Wqb, Wvb, Kb, Qb, Vtb);
  attn_stats<<<dim3(128, 16), 256, 0, stream>>>(Kb, Qb, Ls);
  vscale<<<dim3(4096), 256, 0, stream>>>(Vtb, Ls);
  attn_av<<<dim3(128, 16), 256, 0, stream>>>(Kb, Qb, Vtb, Zb);
  gemm_out<<<dim3(64, 8), 256, 0, stream>>>(Zb, Wob, out);
}

// Round 2
// 286.514 us; speedup vs baseline: 1.0260x; 1.0260x over previous
//
#include <hip/hip_runtime.h>
#include <hip/hip_bf16.h>

// B=8, S=1024, H=16, D=64, E=1024. I/O fp32; internal bf16 MFMA.
// attn = softmax over QUERY axis C (per key row c) of tril(K Q^T)/8.
// Two-pass: l_c = sum_{C<=c} exp(s_cC/8); V pre-scaled by 1/l_c (vscale);
// then z[C] = sum_{c>=C} exp(s_cC/8) * (v_c / l_c).
// R10: attn_av back to single-wave blocks (no barriers; R9's 4-wave barrier
// lockstep exposed load latency every step -> 88.9us). Occupancy fixed by
// 32 C-rows/wave (~115 VGPR -> 4 waves/SIMD vs R8's 2). K ping-pong, V
// loaded just-in-time (hidden under score chain). Grid (128 heads, 32
// chunks): same-head chunks stride 128 ≡ 0 mod 8 -> same XCD, K/V L2-hot.
// attn_stats stays R9 4-wave (no main-loop barriers). GEMMs unchanged.

#define SEQ 1024
#define DH 64
#define NH 16
#define EMB 1024
#define SCALE 0.18033688011112042f  // 0.125 * log2(e)
#define PSTR 40                     // P row stride (u16), 80B = 16B-aligned

#define ZEROM 0
#define DIAGM 1
#define FULLM 2

typedef float f32x4 __attribute__((ext_vector_type(4)));
typedef __bf16 bf16x8 __attribute__((ext_vector_type(8)));
typedef unsigned short u16x8 __attribute__((ext_vector_type(8)));

__device__ __forceinline__ unsigned short f2bf(float f) {
  union { float f; unsigned int u; } v; v.f = f;
  unsigned int u = v.u;
  return (unsigned short)((u + 0x7fffu + ((u >> 16) & 1u)) >> 16);  // RNE
}
__device__ __forceinline__ unsigned short f2bf_fast(float f) {
  union { float f; unsigned int u; } v; v.f = f;
  return (unsigned short)((v.u + 0x8000u) >> 16);  // round-half-up (p>=0)
}
__device__ __forceinline__ float bf2f(unsigned short u) {
  union { unsigned int u; float f; } v; v.u = ((unsigned int)u) << 16; return v.f;
}

__device__ __forceinline__ u16x8 ld8_f32_bf16(const float* g) {
  const float4 a = *(const float4*)g;
  const float4 b = *(const float4*)(g + 4);
  u16x8 r;
  r[0] = f2bf(a.x); r[1] = f2bf(a.y); r[2] = f2bf(a.z); r[3] = f2bf(a.w);
  r[4] = f2bf(b.x); r[5] = f2bf(b.y); r[6] = f2bf(b.z); r[7] = f2bf(b.w);
  return r;
}

__device__ __forceinline__ void gl_lds16(const void* g, void* l) {
  __builtin_amdgcn_global_load_lds(
      (const __attribute__((address_space(1))) void*)g,
      (__attribute__((address_space(3))) void*)l, 16, 0, 0);
}

// ---------------- fp32 -> bf16 conversion of X and weights ----------------
__global__ __launch_bounds__(256) void cvt_bf16(
    const float* __restrict__ X, const float* __restrict__ Wk,
    const float* __restrict__ Wq, const float* __restrict__ Wv,
    const float* __restrict__ Wo,
    unsigned short* __restrict__ Xb, unsigned short* __restrict__ Wkb,
    unsigned short* __restrict__ Wqb, unsigned short* __restrict__ Wvb,
    unsigned short* __restrict__ Wob)
{
  const size_t i = ((size_t)blockIdx.x * 256 + threadIdx.x) * 8;
  const float* src; unsigned short* dst; size_t off;
  if (i < 8388608) { src = X; dst = Xb; off = i; }
  else {
    const size_t j = i - 8388608;
    const int sel = (int)(j >> 20); off = j & 1048575;
    src = (sel == 0) ? Wk : (sel == 1) ? Wq : (sel == 2) ? Wv : Wo;
    dst = (sel == 0) ? Wkb : (sel == 1) ? Wqb : (sel == 2) ? Wvb : Wob;
  }
  *(u16x8*)(dst + off) = ld8_f32_bf16(src + off);
}

// ---------------- GEMM core (BK=64, xor-swizzled LDS) ----------------
#define GEMM_BK64_BODY(Aptr, Bptr)                                              \
  f32x4 acc[4][4] = {};                                                         \
  const int srow = lane >> 3;                                                   \
  const int scol = (((lane & 7) ^ srow)) * 8;                                   \
  const unsigned short* Ag = (Aptr) + (size_t)(mt0 + wave * 32 + srow) * EMB + scol; \
  const unsigned short* Bg = (Bptr) + (size_t)(n0 + wave * 32 + srow) * EMB + scol;  \
  char* lA = (char*)As + wave * 4096;                                           \
  char* lB = (char*)Bs + wave * 4096;                                           \
  for (int k0 = 0; k0 < EMB; k0 += 64) {                                        \
    __syncthreads();                                                            \
    _Pragma("unroll")                                                           \
    for (int ch = 0; ch < 4; ch++) {                                            \
      gl_lds16(Ag + (size_t)ch * 8 * EMB + k0, lA + ch * 1024);                 \
      gl_lds16(Bg + (size_t)ch * 8 * EMB + k0, lB + ch * 1024);                 \
    }                                                                           \
    __syncthreads();                                                            \
    _Pragma("unroll")                                                           \
    for (int half = 0; half < 2; half++) {                                      \
      bf16x8 af[4], bfr[4];                                                     \
      _Pragma("unroll")                                                         \
      for (int t = 0; t < 4; t++) {                                             \
        const int ra = wm * 64 + t * 16 + fr;                                   \
        const int rb = wn * 64 + t * 16 + fr;                                   \
        af[t]  = *(const bf16x8*)&As[ra * 64 + (((half * 4 + quad) ^ (ra & 7)) * 8)]; \
        bfr[t] = *(const bf16x8*)&Bs[rb * 64 + (((half * 4 + quad) ^ (rb & 7)) * 8)]; \
      }                                                                         \
      _Pragma("unroll")                                                         \
      for (int i = 0; i < 4; i++)                                               \
        _Pragma("unroll")                                                       \
        for (int j = 0; j < 4; j++)                                             \
          acc[i][j] = __builtin_amdgcn_mfma_f32_16x16x32_bf16(af[i], bfr[j], acc[i][j], 0, 0, 0); \
    }                                                                           \
  }

// ---------------- GEMM: QKV projection ----------------
__global__ __launch_bounds__(256) void gemm_qkv(
    const unsigned short* __restrict__ X,
    const unsigned short* __restrict__ Wk,
    const unsigned short* __restrict__ Wq,
    const unsigned short* __restrict__ Wv,
    unsigned short* __restrict__ Kb,
    unsigned short* __restrict__ Qb,
    unsigned short* __restrict__ Vt)
{
  __shared__ __align__(16) unsigned short As[128 * 64];
  __shared__ __align__(16) unsigned short Bs[128 * 64];
  const int mt0 = blockIdx.x * 128;
  const int nt = blockIdx.y;
  const int sel = nt >> 3;
  const int n0 = (nt & 7) * 128;
  const unsigned short* W = (sel == 0) ? Wk : (sel == 1) ? Wq : Wv;

  const int tid = threadIdx.x;
  const int wave = tid >> 6, lane = tid & 63;
  const int wm = wave >> 1, wn = wave & 1;
  const int fr = lane & 15, quad = lane >> 4;

  GEMM_BK64_BODY(X, W)

  const int rl = quad * 4;
  if (sel < 2) {
    unsigned short* Dst = (sel == 0) ? Kb : Qb;
#pragma unroll
    for (int i = 0; i < 4; i++) {
      const int col = n0 + wn * 64 + i * 16 + fr;
      const int a = col >> 6, h = col & 63;
#pragma unroll
      for (int j = 0; j < 4; j++) {
        const int rowb = mt0 + wm * 64 + j * 16 + rl;
#pragma unroll
        for (int r = 0; r < 4; r++) {
          const int row = rowb + r;
          const int b = row >> 10, s = row & 1023;
          Dst[(size_t)((b * NH + a) * SEQ + s) * DH + h] = f2bf(acc[j][i][r]);
        }
      }
    }
  } else {
#pragma unroll
    for (int i = 0; i < 4; i++) {
      const int col = n0 + wn * 64 + i * 16 + fr;
      const int a = col >> 6, h = col & 63;
#pragma unroll
      for (int j = 0; j < 4; j++) {
        const int rowb = mt0 + wm * 64 + j * 16 + rl;
#pragma unroll
        for (int r = 0; r < 4; r++) {
          const int row = rowb + r;
          const int b = row >> 10, s = row & 1023;
          Vt[(size_t)((b * NH + a) * DH + h) * SEQ + s] = f2bf(acc[j][i][r]);
        }
      }
    }
  }
}

// ---------------- GEMM: output projection (bf16 in, fp32 out) ----------------
__global__ __launch_bounds__(256) void gemm_out(
    const unsigned short* __restrict__ Z,
    const unsigned short* __restrict__ Wo,
    float* __restrict__ Out)
{
  __shared__ __align__(16) unsigned short As[128 * 64];
  __shared__ __align__(16) unsigned short Bs[128 * 64];
  const int mt0 = blockIdx.x * 128;
  const int n0 = blockIdx.y * 128;

  const int tid = threadIdx.x;
  const int wave = tid >> 6, lane = tid & 63;
  const int wm = wave >> 1, wn = wave & 1;
  const int fr = lane & 15, quad = lane >> 4;

  GEMM_BK64_BODY(Z, Wo)

  const int rl = quad * 4;
#pragma unroll
  for (int i = 0; i < 4; i++) {
    const int col = n0 + wn * 64 + i * 16 + fr;
#pragma unroll
    for (int j = 0; j < 4; j++) {
      const int rowb = mt0 + wm * 64 + j * 16 + rl;
#pragma unroll
      for (int r = 0; r < 4; r++)
        Out[(size_t)(rowb + r) * EMB + col] = acc[j][i][r];
    }
  }
}

// ---------------- stats tile: accumulate exp into l4 ----------------
__device__ __forceinline__ void st_tile(
    const bf16x8* ka, const bf16x8* q, float* l4, int mode, int fr, int quad)
{
  f32x4 a = {0.f, 0.f, 0.f, 0.f};
  a = __builtin_amdgcn_mfma_f32_16x16x32_bf16(ka[0], q[0], a, 0, 0, 0);
  a = __builtin_amdgcn_mfma_f32_16x16x32_bf16(ka[1], q[1], a, 0, 0, 0);
#pragma unroll
  for (int i = 0; i < 4; i++) {
    const float e = exp2f(a[i] * SCALE);
    l4[i] += (mode == FULLM || fr <= quad * 4 + i) ? e : 0.f;
  }
}

// ---------------- Pass 1: l_c = sum_{C<=c} exp(s_cC/8) ----------------
// 4-wave blocks: 64 c-rows per block, waves split query tiles (m mod 4 in
// the full region; wave w takes diag query tile w). Partial l summed via
// LDS. grid (128 heads, 16 chunks), 256 thr. y=0 -> heaviest (jj=15).
__global__ __launch_bounds__(256, 4) void attn_stats(
    const unsigned short* __restrict__ Kb, const unsigned short* __restrict__ Qb,
    float* __restrict__ Ls)
{
  __shared__ float lsum[4][16][64];  // [wave][s*4+i][lane] - conflict-free
  const int head = blockIdx.x;
  const int jj = 15 - (int)blockIdx.y;
  const int cw = jj * 64;
  const int tid = threadIdx.x;
  const int w = tid >> 6;
  const int lane = tid & 63;
  const int fr = lane & 15, quad = lane >> 4;
  const unsigned short* Kl = Kb + (size_t)head * (SEQ * DH) + (size_t)fr * DH + quad * 8;
  const unsigned short* Ql = Qb + (size_t)head * (SEQ * DH) + (size_t)fr * DH + quad * 8;

  // K fragments for this block's 64 c-rows (all waves load the same -> L1 hit)
  bf16x8 ka[4][2];
#pragma unroll
  for (int s = 0; s < 4; s++)
#pragma unroll
    for (int h = 0; h < 2; h++)
      ka[s][h] = *(const bf16x8*)(Kl + (size_t)(cw + s * 16) * DH + h * 32);

  float l[4][4] = {};

  // full region: 16-query tiles m = w + 4*i, i in [0, jj). All tiles FULL.
  if (jj > 0) {
    const unsigned short* q0p = Ql + (size_t)(w * 16) * DH;
    bf16x8 qc0 = *(const bf16x8*)(q0p);
    bf16x8 qc1 = *(const bf16x8*)(q0p + 32);
    for (int i = 0; i < jj; i++) {
      bf16x8 qn0 = qc0, qn1 = qc1;
      if (i + 1 < jj) {
        const unsigned short* qp = Ql + (size_t)((w + 4 * (i + 1)) * 16) * DH;
        qn0 = *(const bf16x8*)(qp);
        qn1 = *(const bf16x8*)(qp + 32);
      }
      bf16x8 qq[2] = {qc0, qc1};
#pragma unroll
      for (int s = 0; s < 4; s++)
        st_tile(ka[s], qq, l[s], FULLM, fr, quad);
      qc0 = qn0; qc1 = qn1;
    }
  }

  // diagonal 64x64 block: wave w covers queries [cw + w*16, cw + w*16 + 16)
  {
    const unsigned short* qp = Ql + (size_t)(cw + w * 16) * DH;
    bf16x8 qd[2];
    qd[0] = *(const bf16x8*)(qp);
    qd[1] = *(const bf16x8*)(qp + 32);
#pragma unroll
    for (int s = 0; s < 4; s++) {
      if (s >= w)
        st_tile(ka[s], qd, l[s], (s == w) ? DIAGM : FULLM, fr, quad);
    }
  }

  // cross-wave reduce, then shfl-over-fr reduce (wave 0)
#pragma unroll
  for (int s = 0; s < 4; s++)
#pragma unroll
    for (int i = 0; i < 4; i++)
      lsum[w][s * 4 + i][lane] = l[s][i];
  __syncthreads();
  if (w == 0) {
#pragma unroll
    for (int s = 0; s < 4; s++)
#pragma unroll
      for (int i = 0; i < 4; i++) {
        float v = lsum[0][s * 4 + i][lane] + lsum[1][s * 4 + i][lane]
                + lsum[2][s * 4 + i][lane] + lsum[3][s * 4 + i][lane];
        v += __shfl_xor(v, 1); v += __shfl_xor(v, 2);
        v += __shfl_xor(v, 4); v += __shfl_xor(v, 8);
        if (fr == 0) Ls[head * SEQ + cw + s * 16 + quad * 4 + i] = v;
      }
  }
}

// ---------------- V row-scale: Vt[head][h][s] *= 1/l_s ----------------
__global__ __launch_bounds__(256) void vscale(
    unsigned short* __restrict__ Vt, const float* __restrict__ Ls)
{
  const size_t i = ((size_t)blockIdx.x * 256 + threadIdx.x) * 8;  // < 8388608
  const int head = (int)(i >> 16);
  const int s = (int)(i & 1023);
  const float* lp = Ls + (head << 10) + s;
  const u16x8 v = *(const u16x8*)(Vt + i);
  const float4 la = *(const float4*)lp;
  const float4 lb = *(const float4*)(lp + 4);
  const float lv[8] = {la.x, la.y, la.z, la.w, lb.x, lb.y, lb.z, lb.w};
  u16x8 o;
#pragma unroll
  for (int j = 0; j < 8; j++)
    o[j] = f2bf(bf2f(v[j]) * __builtin_amdgcn_rcpf(lv[j]));
  *(u16x8*)(Vt + i) = o;
}

// ---------------- av score tile -> LDS (V pre-scaled) ----------------
__device__ __forceinline__ void av_tile(
    const bf16x8* ka, const bf16x8* bq,
    unsigned short* __restrict__ pw, int mode, int fr, int quad)
{
  if (mode == ZEROM) { *(uint2*)pw = make_uint2(0u, 0u); return; }
  f32x4 acc = {0.f, 0.f, 0.f, 0.f};
  acc = __builtin_amdgcn_mfma_f32_16x16x32_bf16(ka[0], bq[0], acc, 0, 0, 0);
  acc = __builtin_amdgcn_mfma_f32_16x16x32_bf16(ka[1], bq[1], acc, 0, 0, 0);
  unsigned short us[4];
#pragma unroll
  for (int i = 0; i < 4; i++) {
    float p = exp2f(acc[i] * SCALE);
    if (mode == DIAGM && (quad * 4 + i < fr)) p = 0.f;
    us[i] = f2bf_fast(p);
  }
  uint2 pk;
  pk.x = (unsigned)us[0] | ((unsigned)us[1] << 16);
  pk.y = (unsigned)us[2] | ((unsigned)us[3] << 16);
  *(uint2*)pw = pk;
}

// ---------------- Pass 2: z = P^T (V/l) ----------------
// Single-wave blocks, 32 C-rows/wave, no barriers (in-wave lgkmcnt only).
// Ping-pong P in LDS; K double-buffered in regs; V loaded just-in-time
// (hidden under the score MFMA+exp chain). ~115 VGPR -> 4 waves/SIMD.
// grid (128 heads, 32 chunks); same-head chunks are 128 apart in linear
// block id (≡0 mod 8) -> same XCD -> K/V stay L2-hot. y=0 heaviest first.
__global__ __launch_bounds__(64, 4) void attn_av(
    const unsigned short* __restrict__ Kb, const unsigned short* __restrict__ Qb,
    const unsigned short* __restrict__ Vt, unsigned short* __restrict__ Z)
{
  __shared__ __align__(16) unsigned short P[2][2][16 * PSTR];
  const int head = blockIdx.x;
  const int j = blockIdx.y;
  const int Cw = j * 32;
  const int lane = threadIdx.x & 63;
  const int fr = lane & 15, quad = lane >> 4;
  const unsigned short* Kl = Kb + (size_t)head * (SEQ * DH) + (size_t)fr * DH + quad * 8;
  const unsigned short* Vl = Vt + (size_t)head * (SEQ * DH) + (size_t)fr * SEQ + quad * 8;

  // Q fragments for this block's 2 query tiles
  bf16x8 bq[2][2];
  {
    const unsigned short* Ql = Qb + (size_t)head * (SEQ * DH)
        + (size_t)(Cw + fr) * DH + quad * 8;
#pragma unroll
    for (int t = 0; t < 2; t++)
#pragma unroll
      for (int h = 0; h < 2; h++)
        bq[t][h] = *(const bf16x8*)(Ql + (size_t)(t * 16) * DH + h * 32);
  }

  f32x4 zacc[2][4] = {};
  bf16x8 kA0[2], kA1[2], kB0[2], kB1[2], vv[4], pf[2];
  unsigned short* Pa = (unsigned short*)&P[0][0][0];
  unsigned short* Pb = (unsigned short*)&P[1][0][0];
  const int pwo = fr * PSTR + quad * 4;  // write col base (u16)
  const int pro = fr * PSTR + quad * 8;  // b128 read offset (u16)

  {  // prologue: scores keys [Cw, Cw+32) -> Pa (diagonal masks)
    bf16x8 k0[2], k1[2];
#pragma unroll
    for (int h = 0; h < 2; h++) {
      k0[h] = *(const bf16x8*)(Kl + (size_t)Cw * DH + h * 32);
      k1[h] = *(const bf16x8*)(Kl + (size_t)(Cw + 16) * DH + h * 32);
    }
    av_tile(k0, bq[0], Pa + pwo, DIAGM, fr, quad);
    av_tile(k0, bq[1], Pa + 16 * PSTR + pwo, ZEROM, fr, quad);
    av_tile(k1, bq[0], Pa + pwo + 16, FULLM, fr, quad);
    av_tile(k1, bq[1], Pa + 16 * PSTR + pwo + 16, DIAGM, fr, quad);
  }
  if (Cw + 32 < SEQ) {  // kA = K rows [Cw+32, Cw+64)
#pragma unroll
    for (int h = 0; h < 2; h++) {
      kA0[h] = *(const bf16x8*)(Kl + (size_t)(Cw + 32) * DH + h * 32);
      kA1[h] = *(const bf16x8*)(Kl + (size_t)(Cw + 48) * DH + h * 32);
    }
  }

  int kb = Cw;
  if (j & 1) {  // odd trip count (32-j): peel one 32-key step
#pragma unroll
    for (int n = 0; n < 4; n++)
      vv[n] = *(const bf16x8*)(Vl + (size_t)(n * 16) * SEQ + kb);
#pragma unroll
    for (int t = 0; t < 2; t++)
      pf[t] = *(const bf16x8*)(Pa + t * 16 * PSTR + pro);
    const bool has2 = (kb + 32 < SEQ);
    if (has2) {  // (kb+96 <= SEQ always holds here for odd j with has2)
#pragma unroll
      for (int h = 0; h < 2; h++) {
        kB0[h] = *(const bf16x8*)(Kl + (size_t)(kb + 64) * DH + h * 32);
        kB1[h] = *(const bf16x8*)(Kl + (size_t)(kb + 80) * DH + h * 32);
      }
      av_tile(kA0, bq[0], Pb + pwo, FULLM, fr, quad);
      av_tile(kA0, bq[1], Pb + 16 * PSTR + pwo, FULLM, fr, quad);
      av_tile(kA1, bq[0], Pb + pwo + 16, FULLM, fr, quad);
      av_tile(kA1, bq[1], Pb + 16 * PSTR + pwo + 16, FULLM, fr, quad);
    }
#pragma unroll
    for (int t = 0; t < 2; t++)
#pragma unroll
      for (int n = 0; n < 4; n++)
        zacc[t][n] = __builtin_amdgcn_mfma_f32_16x16x32_bf16(pf[t], vv[n], zacc[t][n], 0, 0, 0);
    if (has2) {
      kA0[0] = kB0[0]; kA0[1] = kB0[1];
      kA1[0] = kB1[0]; kA1[1] = kB1[1];
      unsigned short* tp = Pa; Pa = Pb; Pb = tp;
    }
    kb += 32;
  }

  for (; kb < SEQ; kb += 64) {  // even # of 32-key steps remain
    {  // step A: PV(Pa, V(kb)); scores(kA = keys [kb+32,kb+64)) -> Pb
#pragma unroll
      for (int n = 0; n < 4; n++)
        vv[n] = *(const bf16x8*)(Vl + (size_t)(n * 16) * SEQ + kb);
#pragma unroll
      for (int t = 0; t < 2; t++)
        pf[t] = *(const bf16x8*)(Pa + t * 16 * PSTR + pro);
      if (kb + 64 < SEQ) {
#pragma unroll
        for (int h = 0; h < 2; h++) {
          kB0[h] = *(const bf16x8*)(Kl + (size_t)(kb + 64) * DH + h * 32);
          kB1[h] = *(const bf16x8*)(Kl + (size_t)(kb + 80) * DH + h * 32);
        }
      }
      av_tile(kA0, bq[0], Pb + pwo, FULLM, fr, quad);
      av_tile(kA0, bq[1], Pb + 16 * PSTR + pwo, FULLM, fr, quad);
      av_tile(kA1, bq[0], Pb + pwo + 16, FULLM, fr, quad);
      av_tile(kA1, bq[1], Pb + 16 * PSTR + pwo + 16, FULLM, fr, quad);
#pragma unroll
      for (int t = 0; t < 2; t++)
#pragma unroll
        for (int n = 0; n < 4; n++)
          zacc[t][n] = __builtin_amdgcn_mfma_f32_16x16x32_bf16(pf[t], vv[n], zacc[t][n], 0, 0, 0);
    }
    {  // step B: PV(Pb, V(kb+32)); scores(kB = keys [kb+64,kb+96)) -> Pa
#pragma unroll
      for (int n = 0; n < 4; n++)
        vv[n] = *(const bf16x8*)(Vl + (size_t)(n * 16) * SEQ + (kb + 32));
#pragma unroll
      for (int t = 0; t < 2; t++)
        pf[t] = *(const bf16x8*)(Pb + t * 16 * PSTR + pro);
      if (kb + 64 < SEQ) {
        if (kb + 96 < SEQ) {
#pragma unroll
          for (int h = 0; h < 2; h++) {
            kA0[h] = *(const bf16x8*)(Kl + (size_t)(kb + 96) * DH + h * 32);
            kA1[h] = *(const bf16x8*)(Kl + (size_t)(kb + 112) * DH + h * 32);
          }
        }
        av_tile(kB0, bq[0], Pa + pwo, FULLM, fr, quad);
        av_tile(kB0, bq[1], Pa + 16 * PSTR + pwo, FULLM, fr, quad);
        av_tile(kB1, bq[0], Pa + pwo + 16, FULLM, fr, quad);
        av_tile(kB1, bq[1], Pa + 16 * PSTR + pwo + 16, FULLM, fr, quad);
      }
#pragma unroll
      for (int t = 0; t < 2; t++)
#pragma unroll
        for (int n = 0; n < 4; n++)
          zacc[t][n] = __builtin_amdgcn_mfma_f32_16x16x32_bf16(pf[t], vv[n], zacc[t][n], 0, 0, 0);
    }
  }

  const int b = head >> 4, a = head & 15;
#pragma unroll
  for (int t = 0; t < 2; t++)
#pragma unroll
    for (int n = 0; n < 4; n++)
#pragma unroll
      for (int i = 0; i < 4; i++) {
        const int C = Cw + t * 16 + quad * 4 + i;
        const int f = a * DH + n * 16 + fr;
        Z[((size_t)(b * SEQ + C) << 10) + f] = f2bf(zacc[t][n][i]);
      }
}

// ---------------- launch ----------------
extern "C" void kernel_launch(void* const* d_in, const int* in_sizes, int n_in,
                              void* d_out, int out_size, void* d_ws, size_t ws_size,
                              hipStream_t stream)
{
  const float* x  = (const float*)d_in[0];
  const float* wk = (const float*)d_in[1];
  const float* wq = (const float*)d_in[2];
  const float* wv = (const float*)d_in[3];
  const float* wo = (const float*)d_in[4];
  float* out = (float*)d_out;
  char* ws = (char*)d_ws;

  unsigned short* Xb  = (unsigned short*)(ws);            // 16 MB (aliased by Zb)
  unsigned short* Zb  = (unsigned short*)(ws);
  unsigned short* Kb  = (unsigned short*)(ws + 16777216);
  unsigned short* Qb  = (unsigned short*)(ws + 33554432);
  unsigned short* Vtb = (unsigned short*)(ws + 50331648);
  unsigned short* Wkb = (unsigned short*)(ws + 67108864);
  unsigned short* Wqb = (unsigned short*)(ws + 69206016);
  unsigned short* Wvb = (unsigned short*)(ws + 71303168);
  unsigned short* Wob = (unsigned short*)(ws + 73400320);
  float* Ls = (float*)(ws + 75497472);

  cvt_bf16<<<dim3(6144), 256, 0, stream>>>(x, wk, wq, wv, wo, Xb, Wkb, Wqb, Wvb, Wob);
  gemm_qkv<<<dim3(64, 24), 256, 0, stream>>>(Xb, Wkb, Wqb, Wvb, Kb, Qb, Vtb);
  attn_stats<<<dim3(128, 16), 256, 0, stream>>>(Kb, Qb, Ls);
  vscale<<<dim3(4096), 256, 0, stream>>>(Vtb, Ls);
  attn_av<<<dim3(128, 32), 64, 0, stream>>>(Kb, Qb, Vtb, Zb);
  gemm_out<<<dim3(64, 8), 256, 0, stream>>>(Zb, Wob, out);
}